// Round 4
// baseline (3857.501 us; speedup 1.0000x reference)
//
#include <hip/hip_runtime.h>
#include <hip/hip_bf16.h>

#define SL 1024
#define DIM 512
#define NH 8
#define HD 64
#define NBUCK 128

__device__ __forceinline__ float silu_f(float x) { return x / (1.0f + __expf(-x)); }

// ---------- h = rmsnorm(hidden) * ln_w, f32 ----------
__global__ void rmsnorm_f32_k(const float* __restrict__ x, const float* __restrict__ w,
                              float* __restrict__ out) {
  int row = blockIdx.x, l = threadIdx.x;  // 64 threads
  const float4* xr = (const float4*)(x + (size_t)row * DIM);
  float4 v0 = xr[l], v1 = xr[l + 64];
  float s = v0.x*v0.x + v0.y*v0.y + v0.z*v0.z + v0.w*v0.w
          + v1.x*v1.x + v1.y*v1.y + v1.z*v1.z + v1.w*v1.w;
  #pragma unroll
  for (int o = 32; o; o >>= 1) s += __shfl_xor(s, o);
  float sc = rsqrtf(s * (1.0f / DIM) + 1e-6f);
  const float4* wr = (const float4*)w;
  float4 w0 = wr[l], w1 = wr[l + 64];
  float4* orow = (float4*)(out + (size_t)row * DIM);
  orow[l]      = make_float4(v0.x*sc*w0.x, v0.y*sc*w0.y, v0.z*sc*w0.z, v0.w*sc*w0.w);
  orow[l + 64] = make_float4(v1.x*sc*w1.x, v1.y*sc*w1.y, v1.z*sc*w1.z, v1.w*sc*w1.w);
}

// ---------- q,k,v,u = silu(h @ W^T); q/k/v in [b,h,l,d] layout, u in [row,col] ----------
__global__ __launch_bounds__(256) void qkvu_naive_k(const float* __restrict__ h,
    const float* __restrict__ wq, const float* __restrict__ wk,
    const float* __restrict__ wv, const float* __restrict__ wu,
    float* __restrict__ q, float* __restrict__ k,
    float* __restrict__ v, float* __restrict__ u) {
  int row = blockIdx.x;                       // 0..4095
  int col = blockIdx.y * 256 + threadIdx.x;   // 0..511
  int mode = blockIdx.z;                      // 0..3
  const float* w = mode == 0 ? wq : mode == 1 ? wk : mode == 2 ? wv : wu;
  const float4* ar = (const float4*)(h + (size_t)row * DIM);
  const float4* br = (const float4*)(w + (size_t)col * DIM);
  float acc = 0.0f;
  for (int kk = 0; kk < DIM / 4; ++kk) {
    float4 a = ar[kk], b = br[kk];
    acc += a.x*b.x + a.y*b.y + a.z*b.z + a.w*b.w;
  }
  float val = silu_f(acc);
  int bb = row >> 10, li = row & 1023, hh = col >> 6, dd = col & 63;
  size_t idx = ((size_t)(bb * NH + hh) * SL + li) * HD + dd;
  if (mode == 0)      q[idx] = val;
  else if (mode == 1) k[idx] = val;
  else if (mode == 2) v[idx] = val;
  else                u[(size_t)row * DIM + col] = val;
}

// ---------- attn[b,h,i,j] = silu(q.k + bias)/L * (j<=i), f32 ----------
__global__ __launch_bounds__(256) void qk_naive_k(const float* __restrict__ q,
    const float* __restrict__ k, const int* __restrict__ ts,
    const float* __restrict__ ts_w, const float* __restrict__ pos_w,
    float* __restrict__ attn) {
  int j = blockIdx.x * 256 + threadIdx.x;  // 0..1023
  int i = blockIdx.y;                      // 0..1023
  int bh = blockIdx.z;                     // 0..31
  float o = 0.0f;
  if (j <= i) {
    const float4* qr = (const float4*)(q + ((size_t)bh * SL + i) * HD);
    const float4* kr = (const float4*)(k + ((size_t)bh * SL + j) * HD);
    float acc = 0.0f;
    #pragma unroll
    for (int d = 0; d < HD / 4; ++d) {
      float4 a = qr[d], b = kr[d];
      acc += a.x*b.x + a.y*b.y + a.z*b.z + a.w*b.w;
    }
    const int* tsb = ts + (size_t)(bh >> 3) * SL;
    int dt = tsb[min(i + 1, SL - 1)] - tsb[j];
    float adf = fmaxf(fabsf((float)dt), 1.0f);
    int bucket = (int)(logf(adf) * (1.0f / 0.301f));
    bucket = bucket > NBUCK ? NBUCK : (bucket < 0 ? 0 : bucket);
    float bias = ts_w[bucket] + pos_w[1023 + j - i];
    o = silu_f(acc + bias) * (1.0f / (float)SL);
  }
  attn[(size_t)bh * SL * SL + (size_t)i * SL + j] = o;
}

// ---------- ao[b,i,h*64+d] = sum_{j<=i} attn[b,h,i,j] * v[b,h,j,d] ----------
__global__ __launch_bounds__(64) void pv_naive_k(const float* __restrict__ attn,
    const float* __restrict__ v, float* __restrict__ ao) {
  int i = blockIdx.x, bh = blockIdx.y, d = threadIdx.x;  // 64 threads = d
  const float* arow = attn + (size_t)bh * SL * SL + (size_t)i * SL;
  const float* vb = v + (size_t)bh * SL * HD + d;
  float acc = 0.0f;
  for (int j = 0; j <= i; ++j)
    acc += arow[j] * vb[(size_t)j * HD];
  int bb = bh >> 3, hh = bh & 7;
  ao[((size_t)bb * SL + i) * DIM + hh * HD + d] = acc;
}

// ---------- gated = u * rmsnorm(ao) * attn_ln_w, f32 ----------
__global__ void gated_naive_k(const float* __restrict__ ao, const float* __restrict__ u,
                              const float* __restrict__ w, float* __restrict__ g) {
  int row = blockIdx.x, l = threadIdx.x;  // 64 threads
  const float4* ar = (const float4*)(ao + (size_t)row * DIM);
  float4 a0 = ar[l], a1 = ar[l + 64];
  float s = a0.x*a0.x + a0.y*a0.y + a0.z*a0.z + a0.w*a0.w
          + a1.x*a1.x + a1.y*a1.y + a1.z*a1.z + a1.w*a1.w;
  #pragma unroll
  for (int o = 32; o; o >>= 1) s += __shfl_xor(s, o);
  float sc = rsqrtf(s * (1.0f / DIM) + 1e-6f);
  const float4* ur = (const float4*)(u + (size_t)row * DIM);
  const float4* wr = (const float4*)w;
  float4 u0 = ur[l], u1 = ur[l + 64], w0 = wr[l], w1 = wr[l + 64];
  float4* gr = (float4*)(g + (size_t)row * DIM);
  gr[l]      = make_float4(u0.x*a0.x*sc*w0.x, u0.y*a0.y*sc*w0.y,
                           u0.z*a0.z*sc*w0.z, u0.w*a0.w*sc*w0.w);
  gr[l + 64] = make_float4(u1.x*a1.x*sc*w1.x, u1.y*a1.y*sc*w1.y,
                           u1.z*a1.z*sc*w1.z, u1.w*a1.w*sc*w1.w);
}

// ---------- out = residual + gated @ wo^T, f32 ----------
__global__ __launch_bounds__(256) void out_naive_k(const float* __restrict__ gated,
    const float* __restrict__ wo, const float* __restrict__ residual,
    float* __restrict__ out) {
  int row = blockIdx.x;
  int col = blockIdx.y * 256 + threadIdx.x;
  const float4* ar = (const float4*)(gated + (size_t)row * DIM);
  const float4* br = (const float4*)(wo + (size_t)col * DIM);
  float acc = 0.0f;
  for (int kk = 0; kk < DIM / 4; ++kk) {
    float4 a = ar[kk], b = br[kk];
    acc += a.x*b.x + a.y*b.y + a.z*b.z + a.w*b.w;
  }
  size_t idx = (size_t)row * DIM + col;
  out[idx] = acc + residual[idx];
}

extern "C" void kernel_launch(void* const* d_in, const int* in_sizes, int n_in,
                              void* d_out, int out_size, void* d_ws, size_t ws_size,
                              hipStream_t stream) {
  const float* hidden    = (const float*)d_in[0];
  // d_in[1] = attention_mask (causal tril) — recomputed analytically
  const int*   ts        = (const int*)d_in[2];
  const float* ln_w      = (const float*)d_in[3];
  const float* attn_ln_w = (const float*)d_in[4];
  const float* wq        = (const float*)d_in[5];
  const float* wk        = (const float*)d_in[6];
  const float* wv        = (const float*)d_in[7];
  const float* wu        = (const float*)d_in[8];
  const float* wo        = (const float*)d_in[9];
  const float* ts_w      = (const float*)d_in[10];
  const float* pos_w     = (const float*)d_in[11];

  // OUTPUTS ARE FLOAT32 (reference output dtype): out [4,1024,512] then attn [4,8,1024,1024]
  float* out  = (float*)d_out;
  float* attn = out + 2097152;

  // f32 workspace: 7 buffers of 4096*512 floats = 56 MiB total
  size_t need = (size_t)7 * 2097152 * 4;
  if (ws_size < need) return;  // diagnostic: error==4.9375 would mean ws too small

  float* h     = (float*)d_ws;         // [4096,512]
  float* q     = h + 2097152;          // [b,h,l,d]
  float* k     = q + 2097152;
  float* v     = k + 2097152;
  float* u     = v + 2097152;          // [4096,512]
  float* gated = u + 2097152;          // [4096,512]
  float* ao    = gated + 2097152;      // [4096,512]

  rmsnorm_f32_k<<<4096, 64, 0, stream>>>(hidden, ln_w, h);
  qkvu_naive_k<<<dim3(4096, 2, 4), 256, 0, stream>>>(h, wq, wk, wv, wu, q, k, v, u);
  qk_naive_k<<<dim3(4, 1024, 32), 256, 0, stream>>>(q, k, ts, ts_w, pos_w, attn);
  pv_naive_k<<<dim3(1024, 32), 64, 0, stream>>>(attn, v, ao);
  gated_naive_k<<<4096, 64, 0, stream>>>(ao, u, attn_ln_w, gated);
  out_naive_k<<<dim3(4096, 2), 256, 0, stream>>>(gated, wo, hidden, out);
}

// Round 5
// 180.259 us; speedup vs baseline: 21.3997x; 21.3997x over previous
//
#include <hip/hip_runtime.h>
#include <hip/hip_bf16.h>

typedef __hip_bfloat16 bf16;
typedef __attribute__((ext_vector_type(8))) short short8;
typedef __attribute__((ext_vector_type(4))) float f32x4;

#define SL 1024
#define DIM 512
#define NH 8
#define HD 64
#define NBUCK 128

__device__ __forceinline__ float silu_f(float x) { return x / (1.0f + __expf(-x)); }

__device__ __forceinline__ short f2bf(float x) {
  bf16 b = __float2bfloat16(x);
  return *reinterpret_cast<short*>(&b);
}

__device__ __forceinline__ void gld_lds16(const void* g, void* l) {
  __builtin_amdgcn_global_load_lds(
      (const __attribute__((address_space(1))) void*)g,
      (__attribute__((address_space(3))) void*)l, 16, 0, 0);
}

// ---------- weight f32 -> bf16 ----------
__global__ void convert_w_k(const float* __restrict__ s0, const float* __restrict__ s1,
                            const float* __restrict__ s2, const float* __restrict__ s3,
                            const float* __restrict__ s4, bf16* __restrict__ dst) {
  int wsel = blockIdx.y;
  const float* src = wsel == 0 ? s0 : wsel == 1 ? s1 : wsel == 2 ? s2 : wsel == 3 ? s3 : s4;
  int i = (blockIdx.x * 256 + threadIdx.x) * 4;
  float4 v = *(const float4*)(src + i);
  bf16* d = dst + (size_t)wsel * DIM * DIM + i;
  d[0] = __float2bfloat16(v.x);
  d[1] = __float2bfloat16(v.y);
  d[2] = __float2bfloat16(v.z);
  d[3] = __float2bfloat16(v.w);
}

// ---------- rmsnorm(hidden) -> bf16 h ----------
__global__ void rmsnorm_k(const float* __restrict__ x, const float* __restrict__ w,
                          bf16* __restrict__ out) {
  int row = blockIdx.x, l = threadIdx.x;  // 64 threads
  const float4* xr = (const float4*)(x + (size_t)row * DIM);
  float4 v0 = xr[l], v1 = xr[l + 64];
  float s = v0.x*v0.x + v0.y*v0.y + v0.z*v0.z + v0.w*v0.w
          + v1.x*v1.x + v1.y*v1.y + v1.z*v1.z + v1.w*v1.w;
  #pragma unroll
  for (int o = 32; o; o >>= 1) s += __shfl_xor(s, o);
  float sc = rsqrtf(s * (1.0f / DIM) + 1e-6f);
  bf16* orow = out + (size_t)row * DIM;
  int c0 = l * 4, c1 = 256 + l * 4;
  orow[c0 + 0] = __float2bfloat16(v0.x * sc * w[c0 + 0]);
  orow[c0 + 1] = __float2bfloat16(v0.y * sc * w[c0 + 1]);
  orow[c0 + 2] = __float2bfloat16(v0.z * sc * w[c0 + 2]);
  orow[c0 + 3] = __float2bfloat16(v0.w * sc * w[c0 + 3]);
  orow[c1 + 0] = __float2bfloat16(v1.x * sc * w[c1 + 0]);
  orow[c1 + 1] = __float2bfloat16(v1.y * sc * w[c1 + 1]);
  orow[c1 + 2] = __float2bfloat16(v1.z * sc * w[c1 + 2]);
  orow[c1 + 3] = __float2bfloat16(v1.w * sc * w[c1 + 3]);
}

// ---------- shared 128x128 GEMM core: C = A(Mx512) * Bt(Nx512)^T ----------
__device__ __forceinline__ void gemm128_core(const bf16* __restrict__ A,
                                             const bf16* __restrict__ Bt,
                                             short* lds, int bm, int bn,
                                             f32x4 acc[4][4]) {
  int t = threadIdx.x, w = t >> 6, l = t & 63;
  int ln = l & 15, g8 = (l >> 4) * 8;
  int wr = (w >> 1) * 64, wc = (w & 1) * 64;
  for (int kt = 0; kt < 16; ++kt) {
    if (kt) __syncthreads();
    #pragma unroll
    for (int i = 0; i < 4; ++i) {
      int s = i * 4 + w;                 // 0..15; 0-7 = A tile, 8-15 = B tile
      int row = s * 16 + (l >> 2);       // within 0..255
      int col = kt * 32 + (l & 3) * 8;
      const bf16* gsrc = (s < 8)
          ? (A  + (size_t)(bm * 128 + row) * DIM + col)
          : (Bt + (size_t)(bn * 128 + row - 128) * DIM + col);
      gld_lds16(gsrc, lds + s * 512 + l * 8);
    }
    __syncthreads();
    short8 a[4], b[4];
    #pragma unroll
    for (int m = 0; m < 4; ++m)
      a[m] = *(const short8*)(lds + (wr + m * 16 + ln) * 32 + g8);
    #pragma unroll
    for (int n = 0; n < 4; ++n)
      b[n] = *(const short8*)(lds + 4096 + (wc + n * 16 + ln) * 32 + g8);
    #pragma unroll
    for (int m = 0; m < 4; ++m)
      #pragma unroll
      for (int n = 0; n < 4; ++n)
        acc[m][n] = __builtin_amdgcn_mfma_f32_16x16x32_bf16(a[m], b[n], acc[m][n], 0, 0, 0);
  }
}

// ---------- q,k,v,u = silu(h @ W^T), scattered into per-head layouts ----------
__global__ __launch_bounds__(256) void gemm_qkvu_k(const bf16* __restrict__ hb,
                                                   const bf16* __restrict__ wb,
                                                   bf16* __restrict__ q, bf16* __restrict__ k,
                                                   bf16* __restrict__ vT, bf16* __restrict__ u) {
  __shared__ __align__(16) short lds[8192];
  int mode = blockIdx.y;
  int bm = blockIdx.x >> 2, bn = blockIdx.x & 3;
  f32x4 acc[4][4];
  #pragma unroll
  for (int m = 0; m < 4; ++m)
    #pragma unroll
    for (int n = 0; n < 4; ++n) { f32x4 z = {0.f, 0.f, 0.f, 0.f}; acc[m][n] = z; }
  gemm128_core(hb, wb + (size_t)mode * DIM * DIM, lds, bm, bn, acc);

  int t = threadIdx.x, w = t >> 6, l = t & 63;
  int ln = l & 15, l4 = (l >> 4) * 4;
  int wr = (w >> 1) * 64, wc = (w & 1) * 64;
  #pragma unroll
  for (int m = 0; m < 4; ++m)
    #pragma unroll
    for (int n = 0; n < 4; ++n)
      #pragma unroll
      for (int j = 0; j < 4; ++j) {
        int rg = bm * 128 + wr + m * 16 + l4 + j;
        int cg = bn * 128 + wc + n * 16 + ln;
        bf16 val = __float2bfloat16(silu_f(acc[m][n][j]));
        int b = rg >> 10, li = rg & 1023, hh = cg >> 6, dd = cg & 63;
        if (mode == 0)      q[((size_t)(b * NH + hh) * SL + li) * HD + dd] = val;
        else if (mode == 1) k[((size_t)(b * NH + hh) * SL + li) * HD + dd] = val;
        else if (mode == 2) vT[((size_t)(b * NH + hh) * HD + dd) * SL + li] = val;
        else                u[(size_t)rg * DIM + cg] = val;
      }
}

// ---------- attn = silu(q k^T + bias)/L * causal, written f32 ----------
__global__ __launch_bounds__(256) void qk_attn_k(const bf16* __restrict__ q,
                                                 const bf16* __restrict__ k,
                                                 const int* __restrict__ ts,
                                                 const float* __restrict__ ts_w,
                                                 const float* __restrict__ pos_w,
                                                 float* __restrict__ attn) {
  int bh = blockIdx.y, ti = blockIdx.x >> 3, tj = blockIdx.x & 7;
  int t = threadIdx.x, w = t >> 6, l = t & 63;
  int ln = l & 15, l4 = (l >> 4) * 4, g8 = (l >> 4) * 8;
  int wr = (w >> 1) * 64, wc = (w & 1) * 64;
  float* arow = attn + (size_t)bh * SL * SL;

  if (tj > ti) {  // fully masked tile: write zeros (buffer is poisoned)
    #pragma unroll
    for (int m = 0; m < 4; ++m)
      #pragma unroll
      for (int n = 0; n < 4; ++n)
        #pragma unroll
        for (int j = 0; j < 4; ++j) {
          int i  = ti * 128 + wr + m * 16 + l4 + j;
          int jj = tj * 128 + wc + n * 16 + ln;
          arow[(size_t)i * SL + jj] = 0.0f;
        }
    return;
  }

  __shared__ __align__(16) short lds[16384];  // q tile [128][64], k tile [128][64]
  #pragma unroll
  for (int i = 0; i < 8; ++i) {
    int s = i * 4 + w;                 // 0..31; 0-15 q, 16-31 k
    int row = (s & 15) * 8 + (l >> 3);
    int col = (l & 7) * 8;
    const bf16* g = (s < 16)
        ? (q + (size_t)bh * SL * HD + (size_t)(ti * 128 + row) * HD + col)
        : (k + (size_t)bh * SL * HD + (size_t)(tj * 128 + row) * HD + col);
    gld_lds16(g, lds + s * 512 + l * 8);
  }
  __syncthreads();

  f32x4 acc[4][4];
  #pragma unroll
  for (int m = 0; m < 4; ++m)
    #pragma unroll
    for (int n = 0; n < 4; ++n) { f32x4 z = {0.f, 0.f, 0.f, 0.f}; acc[m][n] = z; }
  #pragma unroll
  for (int kk = 0; kk < 64; kk += 32) {
    short8 a[4], b[4];
    #pragma unroll
    for (int m = 0; m < 4; ++m)
      a[m] = *(const short8*)(lds + (wr + m * 16 + ln) * 64 + kk + g8);
    #pragma unroll
    for (int n = 0; n < 4; ++n)
      b[n] = *(const short8*)(lds + 8192 + (wc + n * 16 + ln) * 64 + kk + g8);
    #pragma unroll
    for (int m = 0; m < 4; ++m)
      #pragma unroll
      for (int n = 0; n < 4; ++n)
        acc[m][n] = __builtin_amdgcn_mfma_f32_16x16x32_bf16(a[m], b[n], acc[m][n], 0, 0, 0);
  }

  const int* tsb = ts + (size_t)(bh >> 3) * SL;
  #pragma unroll
  for (int m = 0; m < 4; ++m)
    #pragma unroll
    for (int n = 0; n < 4; ++n)
      #pragma unroll
      for (int j = 0; j < 4; ++j) {
        int i  = ti * 128 + wr + m * 16 + l4 + j;
        int jj = tj * 128 + wc + n * 16 + ln;
        float v = acc[m][n][j];
        int dt = tsb[min(i + 1, SL - 1)] - tsb[jj];
        float adf = fmaxf(fabsf((float)dt), 1.0f);
        int bucket = (int)(logf(adf) * (1.0f / 0.301f));
        bucket = bucket < 0 ? 0 : (bucket > NBUCK ? NBUCK : bucket);
        float bias = ts_w[bucket] + pos_w[1023 + jj - i];
        float o = (jj <= i) ? silu_f(v + bias) * (1.0f / (float)SL) : 0.0f;
        arow[(size_t)i * SL + jj] = o;
      }
}

// ---------- attn_out[b,i,h,d] = sum_j attn[b,h,i,j] * v[b,j,h,d] ----------
__global__ __launch_bounds__(256) void pv_k(const float* __restrict__ attn,
                                            const bf16* __restrict__ vT,
                                            float* __restrict__ ao) {
  int bh = blockIdx.y, bm = blockIdx.x;
  int t = threadIdx.x, w = t >> 6, l = t & 63;
  int ln = l & 15, l4 = (l >> 4) * 4, g8 = (l >> 4) * 8;
  __shared__ __align__(16) short lds[6144];  // A tile [128][32] bf16, B tile [64][32]
  const float* arow = attn + (size_t)bh * SL * SL;
  const bf16* vrow = vT + (size_t)bh * HD * SL;
  f32x4 acc[2][4];
  #pragma unroll
  for (int m = 0; m < 2; ++m)
    #pragma unroll
    for (int n = 0; n < 4; ++n) { f32x4 z = {0.f, 0.f, 0.f, 0.f}; acc[m][n] = z; }

  int ktmax = (bm + 1) * 4;  // causal: attn[i][j]==0 for j > i
  for (int kt = 0; kt < ktmax; ++kt) {
    if (kt) __syncthreads();
    // A tile: 8 slices from f32 attn, reg-converted to bf16
    {
      int s = w * 2;                   // wave w covers slices {2w, 2w+1}
      #pragma unroll
      for (int ss = 0; ss < 2; ++ss, ++s) {
        int row = s * 16 + (l >> 2);
        int col = kt * 32 + (l & 3) * 8;
        const float* g = arow + (size_t)(bm * 128 + row) * SL + col;
        float4 f0 = *(const float4*)g;
        float4 f1 = *(const float4*)(g + 4);
        short8 vv;
        vv[0] = f2bf(f0.x); vv[1] = f2bf(f0.y); vv[2] = f2bf(f0.z); vv[3] = f2bf(f0.w);
        vv[4] = f2bf(f1.x); vv[5] = f2bf(f1.y); vv[6] = f2bf(f1.z); vv[7] = f2bf(f1.w);
        *(short8*)(lds + s * 512 + l * 8) = vv;
      }
    }
    // B tile: 4 slices from bf16 vT via async LDS
    {
      int s = 8 + w;
      int r2 = (s - 8) * 16 + (l >> 2);
      int col = kt * 32 + (l & 3) * 8;
      gld_lds16(vrow + (size_t)r2 * SL + col, lds + s * 512 + l * 8);
    }
    __syncthreads();
    short8 a[2], b[4];
    #pragma unroll
    for (int m = 0; m < 2; ++m)
      a[m] = *(const short8*)(lds + (w * 32 + m * 16 + ln) * 32 + g8);
    #pragma unroll
    for (int n = 0; n < 4; ++n)
      b[n] = *(const short8*)(lds + 4096 + (n * 16 + ln) * 32 + g8);
    #pragma unroll
    for (int m = 0; m < 2; ++m)
      #pragma unroll
      for (int n = 0; n < 4; ++n)
        acc[m][n] = __builtin_amdgcn_mfma_f32_16x16x32_bf16(a[m], b[n], acc[m][n], 0, 0, 0);
  }

  int b = bh >> 3, hh = bh & 7;
  #pragma unroll
  for (int m = 0; m < 2; ++m)
    #pragma unroll
    for (int n = 0; n < 4; ++n)
      #pragma unroll
      for (int j = 0; j < 4; ++j) {
        int i = bm * 128 + w * 32 + m * 16 + l4 + j;
        int dd = n * 16 + ln;
        ao[((size_t)(b * SL + i)) * DIM + hh * HD + dd] = acc[m][n][j];
      }
}

// ---------- gated = u * rmsnorm(attn_out) * attn_ln_w ----------
__global__ void gated_k(const float* __restrict__ ao, const bf16* __restrict__ u,
                        const float* __restrict__ w, bf16* __restrict__ g) {
  int row = blockIdx.x, l = threadIdx.x;  // 64 threads
  const float4* ar = (const float4*)(ao + (size_t)row * DIM);
  float4 a0 = ar[l], a1 = ar[l + 64];
  float s = a0.x*a0.x + a0.y*a0.y + a0.z*a0.z + a0.w*a0.w
          + a1.x*a1.x + a1.y*a1.y + a1.z*a1.z + a1.w*a1.w;
  #pragma unroll
  for (int o = 32; o; o >>= 1) s += __shfl_xor(s, o);
  float sc = rsqrtf(s * (1.0f / DIM) + 1e-6f);
  const bf16* ur = u + (size_t)row * DIM;
  bf16* gr = g + (size_t)row * DIM;
  int c0 = l * 4, c1 = 256 + l * 4;
  gr[c0 + 0] = __float2bfloat16(__bfloat162float(ur[c0 + 0]) * a0.x * sc * w[c0 + 0]);
  gr[c0 + 1] = __float2bfloat16(__bfloat162float(ur[c0 + 1]) * a0.y * sc * w[c0 + 1]);
  gr[c0 + 2] = __float2bfloat16(__bfloat162float(ur[c0 + 2]) * a0.z * sc * w[c0 + 2]);
  gr[c0 + 3] = __float2bfloat16(__bfloat162float(ur[c0 + 3]) * a0.w * sc * w[c0 + 3]);
  gr[c1 + 0] = __float2bfloat16(__bfloat162float(ur[c1 + 0]) * a1.x * sc * w[c1 + 0]);
  gr[c1 + 1] = __float2bfloat16(__bfloat162float(ur[c1 + 1]) * a1.y * sc * w[c1 + 1]);
  gr[c1 + 2] = __float2bfloat16(__bfloat162float(ur[c1 + 2]) * a1.z * sc * w[c1 + 2]);
  gr[c1 + 3] = __float2bfloat16(__bfloat162float(ur[c1 + 3]) * a1.w * sc * w[c1 + 3]);
}

// ---------- out = residual + gated @ wo^T, f32 ----------
__global__ __launch_bounds__(256) void gemm_out_k(const bf16* __restrict__ gated,
                                                  const bf16* __restrict__ wob,
                                                  const float* __restrict__ residual,
                                                  float* __restrict__ out) {
  __shared__ __align__(16) short lds[8192];
  int bm = blockIdx.x >> 2, bn = blockIdx.x & 3;
  f32x4 acc[4][4];
  #pragma unroll
  for (int m = 0; m < 4; ++m)
    #pragma unroll
    for (int n = 0; n < 4; ++n) { f32x4 z = {0.f, 0.f, 0.f, 0.f}; acc[m][n] = z; }
  gemm128_core(gated, wob, lds, bm, bn, acc);

  int t = threadIdx.x, w = t >> 6, l = t & 63;
  int ln = l & 15, l4 = (l >> 4) * 4;
  int wr = (w >> 1) * 64, wc = (w & 1) * 64;
  #pragma unroll
  for (int m = 0; m < 4; ++m)
    #pragma unroll
    for (int n = 0; n < 4; ++n)
      #pragma unroll
      for (int j = 0; j < 4; ++j) {
        int rg = bm * 128 + wr + m * 16 + l4 + j;
        int cg = bn * 128 + wc + n * 16 + ln;
        size_t idx = (size_t)rg * DIM + cg;
        out[idx] = acc[m][n][j] + residual[idx];
      }
}

extern "C" void kernel_launch(void* const* d_in, const int* in_sizes, int n_in,
                              void* d_out, int out_size, void* d_ws, size_t ws_size,
                              hipStream_t stream) {
  const float* hidden    = (const float*)d_in[0];
  // d_in[1] = attention_mask (causal tril) — recomputed analytically
  const int*   ts        = (const int*)d_in[2];
  const float* ln_w      = (const float*)d_in[3];
  const float* attn_ln_w = (const float*)d_in[4];
  const float* wq        = (const float*)d_in[5];
  const float* wk        = (const float*)d_in[6];
  const float* wv        = (const float*)d_in[7];
  const float* wu        = (const float*)d_in[8];
  const float* wo        = (const float*)d_in[9];
  const float* ts_w      = (const float*)d_in[10];
  const float* pos_w     = (const float*)d_in[11];

  // OUTPUTS ARE FLOAT32: out [4,1024,512] then attn [4,8,1024,1024]
  float* out  = (float*)d_out;
  float* attn = out + 2097152;

  // workspace (bf16 elements unless noted), ~35 MiB total
  bf16* wb    = (bf16*)d_ws;           // 5 * 512*512
  bf16* hb    = wb + 5 * DIM * DIM;    // [4096,512]
  bf16* q     = hb + 2097152;          // [b,h,l,d]
  bf16* k     = q + 2097152;
  bf16* vT    = k + 2097152;           // [b,h,d,l]
  bf16* u     = vT + 2097152;          // [4096,512]
  bf16* gated = u + 2097152;           // [4096,512]
  float* ao   = (float*)(gated + 2097152);  // [4096,512] f32

  convert_w_k<<<dim3(256, 5), 256, 0, stream>>>(wq, wk, wv, wu, wo, wb);
  rmsnorm_k<<<4096, 64, 0, stream>>>(hidden, ln_w, hb);
  gemm_qkvu_k<<<dim3(128, 4), 256, 0, stream>>>(hb, wb, q, k, vT, u);
  qk_attn_k<<<dim3(64, 32), 256, 0, stream>>>(q, k, ts, ts_w, pos_w, attn);
  pv_k<<<dim3(8, 32), 256, 0, stream>>>(attn, vT, ao);
  gated_k<<<4096, 64, 0, stream>>>(ao, u, attn_ln_w, gated);
  gemm_out_k<<<128, 256, 0, stream>>>(gated, wb + 4 * DIM * DIM, hidden, out);
}

// Round 6
// 136.437 us; speedup vs baseline: 28.2731x; 1.3212x over previous
//
#include <hip/hip_runtime.h>
#include <hip/hip_bf16.h>

typedef __hip_bfloat16 bf16;
typedef __attribute__((ext_vector_type(8))) short short8;
typedef __attribute__((ext_vector_type(4))) float f32x4;

#define SL 1024
#define DIM 512
#define NH 8
#define HD 64
#define NBUCK 128

__device__ __forceinline__ float silu_f(float x) { return x / (1.0f + __expf(-x)); }

__device__ __forceinline__ short f2bf(float x) {
  bf16 b = __float2bfloat16(x);
  return *reinterpret_cast<short*>(&b);
}

__device__ __forceinline__ void gld_lds16(const void* g, void* l) {
  __builtin_amdgcn_global_load_lds(
      (const __attribute__((address_space(1))) void*)g,
      (__attribute__((address_space(3))) void*)l, 16, 0, 0);
}

// ---------- weight f32 -> bf16 ----------
__global__ void convert_w_k(const float* __restrict__ s0, const float* __restrict__ s1,
                            const float* __restrict__ s2, const float* __restrict__ s3,
                            const float* __restrict__ s4, bf16* __restrict__ dst) {
  int wsel = blockIdx.y;
  const float* src = wsel == 0 ? s0 : wsel == 1 ? s1 : wsel == 2 ? s2 : wsel == 3 ? s3 : s4;
  int i = (blockIdx.x * 256 + threadIdx.x) * 4;
  float4 v = *(const float4*)(src + i);
  bf16* d = dst + (size_t)wsel * DIM * DIM + i;
  d[0] = __float2bfloat16(v.x);
  d[1] = __float2bfloat16(v.y);
  d[2] = __float2bfloat16(v.z);
  d[3] = __float2bfloat16(v.w);
}

// ---------- rmsnorm(hidden) -> bf16 h ----------
__global__ void rmsnorm_k(const float* __restrict__ x, const float* __restrict__ w,
                          bf16* __restrict__ out) {
  int row = blockIdx.x, l = threadIdx.x;  // 64 threads
  const float4* xr = (const float4*)(x + (size_t)row * DIM);
  float4 v0 = xr[l], v1 = xr[l + 64];
  float s = v0.x*v0.x + v0.y*v0.y + v0.z*v0.z + v0.w*v0.w
          + v1.x*v1.x + v1.y*v1.y + v1.z*v1.z + v1.w*v1.w;
  #pragma unroll
  for (int o = 32; o; o >>= 1) s += __shfl_xor(s, o);
  float sc = rsqrtf(s * (1.0f / DIM) + 1e-6f);
  bf16* orow = out + (size_t)row * DIM;
  int c0 = l * 4, c1 = 256 + l * 4;
  orow[c0 + 0] = __float2bfloat16(v0.x * sc * w[c0 + 0]);
  orow[c0 + 1] = __float2bfloat16(v0.y * sc * w[c0 + 1]);
  orow[c0 + 2] = __float2bfloat16(v0.z * sc * w[c0 + 2]);
  orow[c0 + 3] = __float2bfloat16(v0.w * sc * w[c0 + 3]);
  orow[c1 + 0] = __float2bfloat16(v1.x * sc * w[c1 + 0]);
  orow[c1 + 1] = __float2bfloat16(v1.y * sc * w[c1 + 1]);
  orow[c1 + 2] = __float2bfloat16(v1.z * sc * w[c1 + 2]);
  orow[c1 + 3] = __float2bfloat16(v1.w * sc * w[c1 + 3]);
}

// ---------- shared 128x128 GEMM core: C = A(Mx512) * Bt(Nx512)^T ----------
__device__ __forceinline__ void gemm128_core(const bf16* __restrict__ A,
                                             const bf16* __restrict__ Bt,
                                             short* lds, int bm, int bn,
                                             f32x4 acc[4][4]) {
  int t = threadIdx.x, w = t >> 6, l = t & 63;
  int ln = l & 15, g8 = (l >> 4) * 8;
  int wr = (w >> 1) * 64, wc = (w & 1) * 64;
  for (int kt = 0; kt < 16; ++kt) {
    if (kt) __syncthreads();
    #pragma unroll
    for (int i = 0; i < 4; ++i) {
      int s = i * 4 + w;                 // 0..15; 0-7 = A tile, 8-15 = B tile
      int row = s * 16 + (l >> 2);       // within 0..255
      int col = kt * 32 + (l & 3) * 8;
      const bf16* gsrc = (s < 8)
          ? (A  + (size_t)(bm * 128 + row) * DIM + col)
          : (Bt + (size_t)(bn * 128 + row - 128) * DIM + col);
      gld_lds16(gsrc, lds + s * 512 + l * 8);
    }
    __syncthreads();
    short8 a[4], b[4];
    #pragma unroll
    for (int m = 0; m < 4; ++m)
      a[m] = *(const short8*)(lds + (wr + m * 16 + ln) * 32 + g8);
    #pragma unroll
    for (int n = 0; n < 4; ++n)
      b[n] = *(const short8*)(lds + 4096 + (wc + n * 16 + ln) * 32 + g8);
    #pragma unroll
    for (int m = 0; m < 4; ++m)
      #pragma unroll
      for (int n = 0; n < 4; ++n)
        acc[m][n] = __builtin_amdgcn_mfma_f32_16x16x32_bf16(a[m], b[n], acc[m][n], 0, 0, 0);
  }
}

// ---------- q,k,v,u = silu(h @ W^T), scattered into per-head layouts ----------
__global__ __launch_bounds__(256) void gemm_qkvu_k(const bf16* __restrict__ hb,
                                                   const bf16* __restrict__ wb,
                                                   bf16* __restrict__ q, bf16* __restrict__ k,
                                                   bf16* __restrict__ vT, bf16* __restrict__ u) {
  __shared__ __align__(16) short lds[8192];
  int mode = blockIdx.y;
  int bm = blockIdx.x >> 2, bn = blockIdx.x & 3;
  f32x4 acc[4][4];
  #pragma unroll
  for (int m = 0; m < 4; ++m)
    #pragma unroll
    for (int n = 0; n < 4; ++n) { f32x4 z = {0.f, 0.f, 0.f, 0.f}; acc[m][n] = z; }
  gemm128_core(hb, wb + (size_t)mode * DIM * DIM, lds, bm, bn, acc);

  int t = threadIdx.x, w = t >> 6, l = t & 63;
  int ln = l & 15, l4 = (l >> 4) * 4;
  int wr = (w >> 1) * 64, wc = (w & 1) * 64;
  #pragma unroll
  for (int m = 0; m < 4; ++m)
    #pragma unroll
    for (int n = 0; n < 4; ++n)
      #pragma unroll
      for (int j = 0; j < 4; ++j) {
        int rg = bm * 128 + wr + m * 16 + l4 + j;
        int cg = bn * 128 + wc + n * 16 + ln;
        bf16 val = __float2bfloat16(silu_f(acc[m][n][j]));
        int b = rg >> 10, li = rg & 1023, hh = cg >> 6, dd = cg & 63;
        if (mode == 0)      q[((size_t)(b * NH + hh) * SL + li) * HD + dd] = val;
        else if (mode == 1) k[((size_t)(b * NH + hh) * SL + li) * HD + dd] = val;
        else if (mode == 2) vT[((size_t)(b * NH + hh) * HD + dd) * SL + li] = val;
        else                u[(size_t)rg * DIM + cg] = val;
      }
}

// ---------- zero strict-upper tiles of attn, coalesced float4 ----------
__global__ __launch_bounds__(256) void zero_upper_k(float* __restrict__ attn) {
  int x = blockIdx.x, bh = blockIdx.y, t = threadIdx.x;
  int ti = 0, acc = 0;
  while (acc + (7 - ti) <= x) { acc += 7 - ti; ++ti; }
  int tj = ti + 1 + (x - acc);
  float* arow = attn + (size_t)bh * SL * SL;
  float4 z = make_float4(0.f, 0.f, 0.f, 0.f);
  #pragma unroll
  for (int rep = 0; rep < 16; ++rep) {
    int flat = rep * 256 + t;          // 0..4095 float4s
    int row = flat >> 5, c4 = flat & 31;
    *(float4*)(arow + (size_t)(ti * 128 + row) * SL + tj * 128 + c4 * 4) = z;
  }
}

// ---------- attn = silu(q k^T + bias)/L, lower-triangle tiles only, f32 ----------
__global__ __launch_bounds__(256) void qk_attn_k(const bf16* __restrict__ q,
                                                 const bf16* __restrict__ k,
                                                 const int* __restrict__ ts,
                                                 const float* __restrict__ ts_w,
                                                 const float* __restrict__ pos_w,
                                                 float* __restrict__ attn) {
  int bh = blockIdx.y, x = blockIdx.x;
  int ti = 0, accx = 0;
  while (accx + ti + 1 <= x) { accx += ti + 1; ++ti; }
  int tj = x - accx;                   // tj <= ti
  int t = threadIdx.x, w = t >> 6, l = t & 63;
  int ln = l & 15, l4 = (l >> 4) * 4, g8 = (l >> 4) * 8;
  int wr = (w >> 1) * 64, wc = (w & 1) * 64;
  float* arow = attn + (size_t)bh * SL * SL;

  __shared__ __align__(16) short lds[16384];  // q tile [128][64], k tile [128][64]
  __shared__ float tw_l[NBUCK + 1];
  __shared__ float pw_l[255];
  __shared__ int tsi_l[128], tsj_l[128];

  const int* tsb = ts + (size_t)(bh >> 3) * SL;
  if (t < NBUCK + 1) tw_l[t] = ts_w[t];
  if (t < 255) pw_l[t] = pos_w[896 + (tj - ti) * 128 + t];
  if (t < 128) tsi_l[t] = tsb[min(ti * 128 + t + 1, SL - 1)];
  else         tsj_l[t - 128] = tsb[tj * 128 + (t - 128)];

  #pragma unroll
  for (int i = 0; i < 8; ++i) {
    int s = i * 4 + w;                 // 0..31; 0-15 q, 16-31 k
    int row = (s & 15) * 8 + (l >> 3);
    int col = (l & 7) * 8;
    const bf16* g = (s < 16)
        ? (q + (size_t)bh * SL * HD + (size_t)(ti * 128 + row) * HD + col)
        : (k + (size_t)bh * SL * HD + (size_t)(tj * 128 + row) * HD + col);
    gld_lds16(g, lds + s * 512 + l * 8);
  }
  __syncthreads();

  f32x4 acc[4][4];
  #pragma unroll
  for (int m = 0; m < 4; ++m)
    #pragma unroll
    for (int n = 0; n < 4; ++n) { f32x4 z = {0.f, 0.f, 0.f, 0.f}; acc[m][n] = z; }
  #pragma unroll
  for (int kk = 0; kk < 64; kk += 32) {
    short8 a[4], b[4];
    #pragma unroll
    for (int m = 0; m < 4; ++m)
      a[m] = *(const short8*)(lds + (wr + m * 16 + ln) * 64 + kk + g8);
    #pragma unroll
    for (int n = 0; n < 4; ++n)
      b[n] = *(const short8*)(lds + 8192 + (wc + n * 16 + ln) * 64 + kk + g8);
    #pragma unroll
    for (int m = 0; m < 4; ++m)
      #pragma unroll
      for (int n = 0; n < 4; ++n)
        acc[m][n] = __builtin_amdgcn_mfma_f32_16x16x32_bf16(a[m], b[n], acc[m][n], 0, 0, 0);
  }

  const float LSC = 2.30281455f;       // ln2 / 0.301
  #pragma unroll
  for (int m = 0; m < 4; ++m)
    #pragma unroll
    for (int j = 0; j < 4; ++j) {
      int il = wr + m * 16 + l4 + j;
      int tsi = tsi_l[il];
      int i = ti * 128 + il;
      #pragma unroll
      for (int n = 0; n < 4; ++n) {
        int jl = wc + n * 16 + ln;
        int jj = tj * 128 + jl;
        float v = acc[m][n][j];
        int dt = tsi - tsj_l[jl];
        float adf = fmaxf(fabsf((float)dt), 1.0f);
        int bucket = (int)(__log2f(adf) * LSC);
        bucket = bucket < 0 ? 0 : (bucket > NBUCK ? NBUCK : bucket);
        float bias = tw_l[bucket] + pw_l[jl - il + 127];
        float o = (jj <= i) ? silu_f(v + bias) * (1.0f / (float)SL) : 0.0f;
        arow[(size_t)i * SL + jj] = o;
      }
    }
}

// ---------- partial attn_out: ao_s[b,i,h,d] = sum_{kt in half s} ... ----------
__global__ __launch_bounds__(256) void pv_k(const float* __restrict__ attn,
                                            const bf16* __restrict__ vT,
                                            float* __restrict__ ao0,
                                            float* __restrict__ ao1) {
  int bh = blockIdx.y, bm = blockIdx.x, sp = blockIdx.z;
  int t = threadIdx.x, w = t >> 6, l = t & 63;
  int ln = l & 15, l4 = (l >> 4) * 4, g8 = (l >> 4) * 8;
  __shared__ __align__(16) short lds[6144];  // A tile [128][32] bf16, B tile [64][32]
  const float* arow = attn + (size_t)bh * SL * SL;
  const bf16* vrow = vT + (size_t)bh * HD * SL;
  f32x4 acc[2][4];
  #pragma unroll
  for (int m = 0; m < 2; ++m)
    #pragma unroll
    for (int n = 0; n < 4; ++n) { f32x4 z = {0.f, 0.f, 0.f, 0.f}; acc[m][n] = z; }

  int klo = sp * (bm + 1) * 2;         // half of ktmax=(bm+1)*4
  int khi = (sp + 1) * (bm + 1) * 2;
  for (int kt = klo; kt < khi; ++kt) {
    if (kt > klo) __syncthreads();
    // A tile: 8 slices from f32 attn, reg-converted to bf16
    {
      int s = w * 2;                   // wave w covers slices {2w, 2w+1}
      #pragma unroll
      for (int ss = 0; ss < 2; ++ss, ++s) {
        int row = s * 16 + (l >> 2);
        int col = kt * 32 + (l & 3) * 8;
        const float* g = arow + (size_t)(bm * 128 + row) * SL + col;
        float4 f0 = *(const float4*)g;
        float4 f1 = *(const float4*)(g + 4);
        short8 vv;
        vv[0] = f2bf(f0.x); vv[1] = f2bf(f0.y); vv[2] = f2bf(f0.z); vv[3] = f2bf(f0.w);
        vv[4] = f2bf(f1.x); vv[5] = f2bf(f1.y); vv[6] = f2bf(f1.z); vv[7] = f2bf(f1.w);
        *(short8*)(lds + s * 512 + l * 8) = vv;
      }
    }
    // B tile: 4 slices from bf16 vT via async LDS
    {
      int s = 8 + w;
      int r2 = (s - 8) * 16 + (l >> 2);
      int col = kt * 32 + (l & 3) * 8;
      gld_lds16(vrow + (size_t)r2 * SL + col, lds + s * 512 + l * 8);
    }
    __syncthreads();
    short8 a[2], b[4];
    #pragma unroll
    for (int m = 0; m < 2; ++m)
      a[m] = *(const short8*)(lds + (w * 32 + m * 16 + ln) * 32 + g8);
    #pragma unroll
    for (int n = 0; n < 4; ++n)
      b[n] = *(const short8*)(lds + 4096 + (n * 16 + ln) * 32 + g8);
    #pragma unroll
    for (int m = 0; m < 2; ++m)
      #pragma unroll
      for (int n = 0; n < 4; ++n)
        acc[m][n] = __builtin_amdgcn_mfma_f32_16x16x32_bf16(a[m], b[n], acc[m][n], 0, 0, 0);
  }

  float* aop = sp == 0 ? ao0 : ao1;
  int b = bh >> 3, hh = bh & 7;
  #pragma unroll
  for (int m = 0; m < 2; ++m)
    #pragma unroll
    for (int n = 0; n < 4; ++n)
      #pragma unroll
      for (int j = 0; j < 4; ++j) {
        int i = bm * 128 + w * 32 + m * 16 + l4 + j;
        int dd = n * 16 + ln;
        aop[((size_t)(b * SL + i)) * DIM + hh * HD + dd] = acc[m][n][j];
      }
}

// ---------- gated = u * rmsnorm(ao0+ao1) * attn_ln_w ----------
__global__ void gated_k(const float* __restrict__ ao0, const float* __restrict__ ao1,
                        const bf16* __restrict__ u,
                        const float* __restrict__ w, bf16* __restrict__ g) {
  int row = blockIdx.x, l = threadIdx.x;  // 64 threads
  const float4* ar0 = (const float4*)(ao0 + (size_t)row * DIM);
  const float4* ar1 = (const float4*)(ao1 + (size_t)row * DIM);
  float4 p0 = ar0[l], p1 = ar1[l], p2 = ar0[l + 64], p3 = ar1[l + 64];
  float4 a0 = make_float4(p0.x + p1.x, p0.y + p1.y, p0.z + p1.z, p0.w + p1.w);
  float4 a1 = make_float4(p2.x + p3.x, p2.y + p3.y, p2.z + p3.z, p2.w + p3.w);
  float s = a0.x*a0.x + a0.y*a0.y + a0.z*a0.z + a0.w*a0.w
          + a1.x*a1.x + a1.y*a1.y + a1.z*a1.z + a1.w*a1.w;
  #pragma unroll
  for (int o = 32; o; o >>= 1) s += __shfl_xor(s, o);
  float sc = rsqrtf(s * (1.0f / DIM) + 1e-6f);
  const bf16* ur = u + (size_t)row * DIM;
  bf16* gr = g + (size_t)row * DIM;
  int c0 = l * 4, c1 = 256 + l * 4;
  gr[c0 + 0] = __float2bfloat16(__bfloat162float(ur[c0 + 0]) * a0.x * sc * w[c0 + 0]);
  gr[c0 + 1] = __float2bfloat16(__bfloat162float(ur[c0 + 1]) * a0.y * sc * w[c0 + 1]);
  gr[c0 + 2] = __float2bfloat16(__bfloat162float(ur[c0 + 2]) * a0.z * sc * w[c0 + 2]);
  gr[c0 + 3] = __float2bfloat16(__bfloat162float(ur[c0 + 3]) * a0.w * sc * w[c0 + 3]);
  gr[c1 + 0] = __float2bfloat16(__bfloat162float(ur[c1 + 0]) * a1.x * sc * w[c1 + 0]);
  gr[c1 + 1] = __float2bfloat16(__bfloat162float(ur[c1 + 1]) * a1.y * sc * w[c1 + 1]);
  gr[c1 + 2] = __float2bfloat16(__bfloat162float(ur[c1 + 2]) * a1.z * sc * w[c1 + 2]);
  gr[c1 + 3] = __float2bfloat16(__bfloat162float(ur[c1 + 3]) * a1.w * sc * w[c1 + 3]);
}

// ---------- out = residual + gated @ wo^T, f32 ----------
__global__ __launch_bounds__(256) void gemm_out_k(const bf16* __restrict__ gated,
                                                  const bf16* __restrict__ wob,
                                                  const float* __restrict__ residual,
                                                  float* __restrict__ out) {
  __shared__ __align__(16) short lds[8192];
  int bm = blockIdx.x >> 2, bn = blockIdx.x & 3;
  f32x4 acc[4][4];
  #pragma unroll
  for (int m = 0; m < 4; ++m)
    #pragma unroll
    for (int n = 0; n < 4; ++n) { f32x4 z = {0.f, 0.f, 0.f, 0.f}; acc[m][n] = z; }
  gemm128_core(gated, wob, lds, bm, bn, acc);

  int t = threadIdx.x, w = t >> 6, l = t & 63;
  int ln = l & 15, l4 = (l >> 4) * 4;
  int wr = (w >> 1) * 64, wc = (w & 1) * 64;
  #pragma unroll
  for (int m = 0; m < 4; ++m)
    #pragma unroll
    for (int n = 0; n < 4; ++n)
      #pragma unroll
      for (int j = 0; j < 4; ++j) {
        int rg = bm * 128 + wr + m * 16 + l4 + j;
        int cg = bn * 128 + wc + n * 16 + ln;
        size_t idx = (size_t)rg * DIM + cg;
        out[idx] = acc[m][n][j] + residual[idx];
      }
}

extern "C" void kernel_launch(void* const* d_in, const int* in_sizes, int n_in,
                              void* d_out, int out_size, void* d_ws, size_t ws_size,
                              hipStream_t stream) {
  const float* hidden    = (const float*)d_in[0];
  // d_in[1] = attention_mask (causal tril) — recomputed analytically
  const int*   ts        = (const int*)d_in[2];
  const float* ln_w      = (const float*)d_in[3];
  const float* attn_ln_w = (const float*)d_in[4];
  const float* wq        = (const float*)d_in[5];
  const float* wk        = (const float*)d_in[6];
  const float* wv        = (const float*)d_in[7];
  const float* wu        = (const float*)d_in[8];
  const float* wo        = (const float*)d_in[9];
  const float* ts_w      = (const float*)d_in[10];
  const float* pos_w     = (const float*)d_in[11];

  // OUTPUTS ARE FLOAT32: out [4,1024,512] then attn [4,8,1024,1024]
  float* out  = (float*)d_out;
  float* attn = out + 2097152;

  // workspace (~44.6 MiB < proven 56 MiB)
  bf16* wb    = (bf16*)d_ws;           // 5 * 512*512
  bf16* hb    = wb + 5 * DIM * DIM;    // [4096,512]
  bf16* q     = hb + 2097152;          // [b,h,l,d]
  bf16* k     = q + 2097152;
  bf16* vT    = k + 2097152;           // [b,h,d,l]
  bf16* u     = vT + 2097152;          // [4096,512]
  bf16* gated = u + 2097152;           // [4096,512]
  float* ao0  = (float*)(gated + 2097152);  // [4096,512] f32
  float* ao1  = ao0 + 2097152;              // [4096,512] f32

  convert_w_k<<<dim3(256, 5), 256, 0, stream>>>(wq, wk, wv, wu, wo, wb);
  rmsnorm_k<<<4096, 64, 0, stream>>>(hidden, ln_w, hb);
  gemm_qkvu_k<<<dim3(128, 4), 256, 0, stream>>>(hb, wb, q, k, vT, u);
  zero_upper_k<<<dim3(28, 32), 256, 0, stream>>>(attn);
  qk_attn_k<<<dim3(36, 32), 256, 0, stream>>>(q, k, ts, ts_w, pos_w, attn);
  pv_k<<<dim3(8, 32, 2), 256, 0, stream>>>(attn, vT, ao0, ao1);
  gated_k<<<4096, 64, 0, stream>>>(ao0, ao1, u, attn_ln_w, gated);
  gemm_out_k<<<128, 256, 0, stream>>>(gated, wb + 4 * DIM * DIM, hidden, out);
}

// Round 7
// 122.142 us; speedup vs baseline: 31.5821x; 1.1170x over previous
//
#include <hip/hip_runtime.h>
#include <hip/hip_bf16.h>

typedef __hip_bfloat16 bf16;
typedef __attribute__((ext_vector_type(8))) short short8;
typedef __attribute__((ext_vector_type(4))) float f32x4;

#define SL 1024
#define DIM 512
#define NH 8
#define HD 64
#define NBUCK 128

__device__ __forceinline__ float silu_f(float x) { return x / (1.0f + __expf(-x)); }

__device__ __forceinline__ short f2bf(float x) {
  bf16 b = __float2bfloat16(x);
  return *reinterpret_cast<short*>(&b);
}

__device__ __forceinline__ void gld_lds16(const void* g, void* l) {
  __builtin_amdgcn_global_load_lds(
      (const __attribute__((address_space(1))) void*)g,
      (__attribute__((address_space(3))) void*)l, 16, 0, 0);
}

// ---------- weight f32 -> bf16 ----------
__global__ void convert_w_k(const float* __restrict__ s0, const float* __restrict__ s1,
                            const float* __restrict__ s2, const float* __restrict__ s3,
                            const float* __restrict__ s4, bf16* __restrict__ dst) {
  int wsel = blockIdx.y;
  const float* src = wsel == 0 ? s0 : wsel == 1 ? s1 : wsel == 2 ? s2 : wsel == 3 ? s3 : s4;
  int i = (blockIdx.x * 256 + threadIdx.x) * 4;
  float4 v = *(const float4*)(src + i);
  bf16* d = dst + (size_t)wsel * DIM * DIM + i;
  d[0] = __float2bfloat16(v.x);
  d[1] = __float2bfloat16(v.y);
  d[2] = __float2bfloat16(v.z);
  d[3] = __float2bfloat16(v.w);
}

// ---------- rmsnorm(hidden) -> bf16 h ----------
__global__ void rmsnorm_k(const float* __restrict__ x, const float* __restrict__ w,
                          bf16* __restrict__ out) {
  int row = blockIdx.x, l = threadIdx.x;  // 64 threads
  const float4* xr = (const float4*)(x + (size_t)row * DIM);
  float4 v0 = xr[l], v1 = xr[l + 64];
  float s = v0.x*v0.x + v0.y*v0.y + v0.z*v0.z + v0.w*v0.w
          + v1.x*v1.x + v1.y*v1.y + v1.z*v1.z + v1.w*v1.w;
  #pragma unroll
  for (int o = 32; o; o >>= 1) s += __shfl_xor(s, o);
  float sc = rsqrtf(s * (1.0f / DIM) + 1e-6f);
  bf16* orow = out + (size_t)row * DIM;
  int c0 = l * 4, c1 = 256 + l * 4;
  orow[c0 + 0] = __float2bfloat16(v0.x * sc * w[c0 + 0]);
  orow[c0 + 1] = __float2bfloat16(v0.y * sc * w[c0 + 1]);
  orow[c0 + 2] = __float2bfloat16(v0.z * sc * w[c0 + 2]);
  orow[c0 + 3] = __float2bfloat16(v0.w * sc * w[c0 + 3]);
  orow[c1 + 0] = __float2bfloat16(v1.x * sc * w[c1 + 0]);
  orow[c1 + 1] = __float2bfloat16(v1.y * sc * w[c1 + 1]);
  orow[c1 + 2] = __float2bfloat16(v1.z * sc * w[c1 + 2]);
  orow[c1 + 3] = __float2bfloat16(v1.w * sc * w[c1 + 3]);
}

// ---------- shared 128x128 GEMM core: C = A(Mx512) * Bt(Nx512)^T ----------
__device__ __forceinline__ void gemm128_core(const bf16* __restrict__ A,
                                             const bf16* __restrict__ Bt,
                                             short* lds, int bm, int bn,
                                             f32x4 acc[4][4]) {
  int t = threadIdx.x, w = t >> 6, l = t & 63;
  int ln = l & 15, g8 = (l >> 4) * 8;
  int wr = (w >> 1) * 64, wc = (w & 1) * 64;
  for (int kt = 0; kt < 16; ++kt) {
    if (kt) __syncthreads();
    #pragma unroll
    for (int i = 0; i < 4; ++i) {
      int s = i * 4 + w;                 // 0..15; 0-7 = A tile, 8-15 = B tile
      int row = s * 16 + (l >> 2);       // within 0..255
      int col = kt * 32 + (l & 3) * 8;
      const bf16* gsrc = (s < 8)
          ? (A  + (size_t)(bm * 128 + row) * DIM + col)
          : (Bt + (size_t)(bn * 128 + row - 128) * DIM + col);
      gld_lds16(gsrc, lds + s * 512 + l * 8);
    }
    __syncthreads();
    short8 a[4], b[4];
    #pragma unroll
    for (int m = 0; m < 4; ++m)
      a[m] = *(const short8*)(lds + (wr + m * 16 + ln) * 32 + g8);
    #pragma unroll
    for (int n = 0; n < 4; ++n)
      b[n] = *(const short8*)(lds + 4096 + (wc + n * 16 + ln) * 32 + g8);
    #pragma unroll
    for (int m = 0; m < 4; ++m)
      #pragma unroll
      for (int n = 0; n < 4; ++n)
        acc[m][n] = __builtin_amdgcn_mfma_f32_16x16x32_bf16(a[m], b[n], acc[m][n], 0, 0, 0);
  }
}

// ---------- q,k,v,u = silu(h @ W^T); q/k/v in [b,h,l,d], u row-major ----------
__global__ __launch_bounds__(256) void gemm_qkvu_k(const bf16* __restrict__ hb,
                                                   const bf16* __restrict__ wb,
                                                   bf16* __restrict__ q, bf16* __restrict__ k,
                                                   bf16* __restrict__ v, bf16* __restrict__ u) {
  __shared__ __align__(16) short lds[8192];
  int mode = blockIdx.y;
  int bm = blockIdx.x >> 2, bn = blockIdx.x & 3;
  f32x4 acc[4][4];
  #pragma unroll
  for (int m = 0; m < 4; ++m)
    #pragma unroll
    for (int n = 0; n < 4; ++n) { f32x4 z = {0.f, 0.f, 0.f, 0.f}; acc[m][n] = z; }
  gemm128_core(hb, wb + (size_t)mode * DIM * DIM, lds, bm, bn, acc);

  int t = threadIdx.x, w = t >> 6, l = t & 63;
  int ln = l & 15, l4 = (l >> 4) * 4;
  int wr = (w >> 1) * 64, wc = (w & 1) * 64;
  bf16* qkv = mode == 0 ? q : mode == 1 ? k : v;
  #pragma unroll
  for (int m = 0; m < 4; ++m)
    #pragma unroll
    for (int n = 0; n < 4; ++n)
      #pragma unroll
      for (int j = 0; j < 4; ++j) {
        int rg = bm * 128 + wr + m * 16 + l4 + j;
        int cg = bn * 128 + wc + n * 16 + ln;
        bf16 val = __float2bfloat16(silu_f(acc[m][n][j]));
        int b = rg >> 10, li = rg & 1023, hh = cg >> 6, dd = cg & 63;
        if (mode <= 2) qkv[((size_t)(b * NH + hh) * SL + li) * HD + dd] = val;
        else           u[(size_t)rg * DIM + cg] = val;
      }
}

// ---------- vT[b,h,d,l] = transpose(v[b,h,l,d]), coalesced both sides ----------
__global__ __launch_bounds__(256) void transpose_v_k(const bf16* __restrict__ v,
                                                     bf16* __restrict__ vT) {
  int bh = blockIdx.y, t0 = blockIdx.x * 64;
  int t = threadIdx.x;
  __shared__ short ldsT[64 * 65];
  const bf16* vb = v + (size_t)bh * SL * HD;
  bf16* vtb = vT + (size_t)bh * HD * SL;
  int r = t >> 2, c = (t & 3) * 16;
  short8 x0 = *(const short8*)(vb + (size_t)(t0 + r) * HD + c);
  short8 x1 = *(const short8*)(vb + (size_t)(t0 + r) * HD + c + 8);
  #pragma unroll
  for (int qq = 0; qq < 8; ++qq) {
    ldsT[r * 65 + c + qq] = x0[qq];
    ldsT[r * 65 + c + 8 + qq] = x1[qq];
  }
  __syncthreads();
  int d = t >> 2, lc = (t & 3) * 16;
  short8 y0, y1;
  #pragma unroll
  for (int qq = 0; qq < 8; ++qq) {
    y0[qq] = ldsT[(lc + qq) * 65 + d];
    y1[qq] = ldsT[(lc + 8 + qq) * 65 + d];
  }
  bf16* dst = vtb + (size_t)d * SL + t0 + lc;
  *(short8*)dst = y0;
  *(short8*)(dst + 8) = y1;
}

// ---------- attn = silu(q k^T + bias)/L, lower tiles + folded zero tiles ----------
__global__ __launch_bounds__(256) void qk_attn_k(const bf16* __restrict__ q,
                                                 const bf16* __restrict__ k,
                                                 const int* __restrict__ ts,
                                                 const float* __restrict__ ts_w,
                                                 const float* __restrict__ pos_w,
                                                 float* __restrict__ attn) {
  int bh = blockIdx.y, x = blockIdx.x;
  int ti = 0, accx = 0;
  while (accx + ti + 1 <= x) { accx += ti + 1; ++ti; }
  int tj = x - accx;                   // tj <= ti
  int t = threadIdx.x, w = t >> 6, l = t & 63;
  int ln = l & 15, l4 = (l >> 4) * 4, g8 = (l >> 4) * 8;
  int wr = (w >> 1) * 64, wc = (w & 1) * 64;
  float* arow = attn + (size_t)bh * SL * SL;

  __shared__ __align__(16) short lds[16384];  // q tile [128][64], k tile [128][64]
  __shared__ float tw_l[NBUCK + 1];
  __shared__ float pw_l[255];
  __shared__ int tsi_l[128], tsj_l[128];

  const int* tsb = ts + (size_t)(bh >> 3) * SL;
  if (t < NBUCK + 1) tw_l[t] = ts_w[t];
  if (t < 255) pw_l[t] = pos_w[896 + (tj - ti) * 128 + t];
  if (t < 128) tsi_l[t] = tsb[min(ti * 128 + t + 1, SL - 1)];
  else         tsj_l[t - 128] = tsb[tj * 128 + (t - 128)];

  #pragma unroll
  for (int i = 0; i < 8; ++i) {
    int s = i * 4 + w;                 // 0..31; 0-15 q, 16-31 k
    int row = (s & 15) * 8 + (l >> 3);
    int col = (l & 7) * 8;
    const bf16* g = (s < 16)
        ? (q + (size_t)bh * SL * HD + (size_t)(ti * 128 + row) * HD + col)
        : (k + (size_t)bh * SL * HD + (size_t)(tj * 128 + row) * HD + col);
    gld_lds16(g, lds + s * 512 + l * 8);
  }
  __syncthreads();

  f32x4 acc[4][4];
  #pragma unroll
  for (int m = 0; m < 4; ++m)
    #pragma unroll
    for (int n = 0; n < 4; ++n) { f32x4 z = {0.f, 0.f, 0.f, 0.f}; acc[m][n] = z; }
  #pragma unroll
  for (int kk = 0; kk < 64; kk += 32) {
    short8 a[4], b[4];
    #pragma unroll
    for (int m = 0; m < 4; ++m)
      a[m] = *(const short8*)(lds + (wr + m * 16 + ln) * 64 + kk + g8);
    #pragma unroll
    for (int n = 0; n < 4; ++n)
      b[n] = *(const short8*)(lds + 8192 + (wc + n * 16 + ln) * 64 + kk + g8);
    #pragma unroll
    for (int m = 0; m < 4; ++m)
      #pragma unroll
      for (int n = 0; n < 4; ++n)
        acc[m][n] = __builtin_amdgcn_mfma_f32_16x16x32_bf16(a[m], b[n], acc[m][n], 0, 0, 0);
  }

  const float LSC = 2.30281455f;       // ln2 / 0.301
  #pragma unroll
  for (int m = 0; m < 4; ++m)
    #pragma unroll
    for (int j = 0; j < 4; ++j) {
      int il = wr + m * 16 + l4 + j;
      int tsi = tsi_l[il];
      int i = ti * 128 + il;
      #pragma unroll
      for (int n = 0; n < 4; ++n) {
        int jl = wc + n * 16 + ln;
        int jj = tj * 128 + jl;
        float v = acc[m][n][j];
        int dt = tsi - tsj_l[jl];
        float adf = fmaxf(fabsf((float)dt), 1.0f);
        int bucket = (int)(__log2f(adf) * LSC);
        bucket = bucket < 0 ? 0 : (bucket > NBUCK ? NBUCK : bucket);
        float bias = tw_l[bucket] + pw_l[jl - il + 127];
        float o = (jj <= i) ? silu_f(v + bias) * (1.0f / (float)SL) : 0.0f;
        arow[(size_t)i * SL + jj] = o;
      }
    }

  // folded zero-fill of one strict-upper tile (28 tiles over blocks 0..27)
  if (x < 28) {
    int zi = 0, acc2 = 0;
    while (acc2 + (7 - zi) <= x) { acc2 += 7 - zi; ++zi; }
    int zj = zi + 1 + (x - acc2);
    float4 z4 = make_float4(0.f, 0.f, 0.f, 0.f);
    #pragma unroll
    for (int rep = 0; rep < 16; ++rep) {
      int flat = rep * 256 + t;
      int row = flat >> 5, c4 = flat & 31;
      *(float4*)(arow + (size_t)(zi * 128 + row) * SL + zj * 128 + c4 * 4) = z4;
    }
  }
}

// ---------- partial attn_out: ao_s[b,i,h,d] = sum_{kt in half s} ... ----------
__global__ __launch_bounds__(256) void pv_k(const float* __restrict__ attn,
                                            const bf16* __restrict__ vT,
                                            float* __restrict__ ao0,
                                            float* __restrict__ ao1) {
  int bh = blockIdx.y, bm = blockIdx.x, sp = blockIdx.z;
  int t = threadIdx.x, w = t >> 6, l = t & 63;
  int ln = l & 15, l4 = (l >> 4) * 4, g8 = (l >> 4) * 8;
  __shared__ __align__(16) short lds[6144];  // A tile [128][32] bf16, B tile [64][32]
  const float* arow = attn + (size_t)bh * SL * SL;
  const bf16* vrow = vT + (size_t)bh * HD * SL;
  f32x4 acc[2][4];
  #pragma unroll
  for (int m = 0; m < 2; ++m)
    #pragma unroll
    for (int n = 0; n < 4; ++n) { f32x4 z = {0.f, 0.f, 0.f, 0.f}; acc[m][n] = z; }

  int klo = sp * (bm + 1) * 2;         // half of ktmax=(bm+1)*4
  int khi = (sp + 1) * (bm + 1) * 2;
  for (int kt = klo; kt < khi; ++kt) {
    if (kt > klo) __syncthreads();
    // A tile: 8 slices from f32 attn, reg-converted to bf16
    {
      int s = w * 2;                   // wave w covers slices {2w, 2w+1}
      #pragma unroll
      for (int ss = 0; ss < 2; ++ss, ++s) {
        int row = s * 16 + (l >> 2);
        int col = kt * 32 + (l & 3) * 8;
        const float* g = arow + (size_t)(bm * 128 + row) * SL + col;
        float4 f0 = *(const float4*)g;
        float4 f1 = *(const float4*)(g + 4);
        short8 vv;
        vv[0] = f2bf(f0.x); vv[1] = f2bf(f0.y); vv[2] = f2bf(f0.z); vv[3] = f2bf(f0.w);
        vv[4] = f2bf(f1.x); vv[5] = f2bf(f1.y); vv[6] = f2bf(f1.z); vv[7] = f2bf(f1.w);
        *(short8*)(lds + s * 512 + l * 8) = vv;
      }
    }
    // B tile: 4 slices from bf16 vT via async LDS
    {
      int s = 8 + w;
      int r2 = (s - 8) * 16 + (l >> 2);
      int col = kt * 32 + (l & 3) * 8;
      gld_lds16(vrow + (size_t)r2 * SL + col, lds + s * 512 + l * 8);
    }
    __syncthreads();
    short8 a[2], b[4];
    #pragma unroll
    for (int m = 0; m < 2; ++m)
      a[m] = *(const short8*)(lds + (w * 32 + m * 16 + ln) * 32 + g8);
    #pragma unroll
    for (int n = 0; n < 4; ++n)
      b[n] = *(const short8*)(lds + 4096 + (n * 16 + ln) * 32 + g8);
    #pragma unroll
    for (int m = 0; m < 2; ++m)
      #pragma unroll
      for (int n = 0; n < 4; ++n)
        acc[m][n] = __builtin_amdgcn_mfma_f32_16x16x32_bf16(a[m], b[n], acc[m][n], 0, 0, 0);
  }

  float* aop = sp == 0 ? ao0 : ao1;
  int b = bh >> 3, hh = bh & 7;
  #pragma unroll
  for (int m = 0; m < 2; ++m)
    #pragma unroll
    for (int n = 0; n < 4; ++n)
      #pragma unroll
      for (int j = 0; j < 4; ++j) {
        int i = bm * 128 + w * 32 + m * 16 + l4 + j;
        int dd = n * 16 + ln;
        aop[((size_t)(b * SL + i)) * DIM + hh * HD + dd] = acc[m][n][j];
      }
}

// ---------- gated = u * rmsnorm(ao0+ao1) * attn_ln_w ----------
__global__ void gated_k(const float* __restrict__ ao0, const float* __restrict__ ao1,
                        const bf16* __restrict__ u,
                        const float* __restrict__ w, bf16* __restrict__ g) {
  int row = blockIdx.x, l = threadIdx.x;  // 64 threads
  const float4* ar0 = (const float4*)(ao0 + (size_t)row * DIM);
  const float4* ar1 = (const float4*)(ao1 + (size_t)row * DIM);
  float4 p0 = ar0[l], p1 = ar1[l], p2 = ar0[l + 64], p3 = ar1[l + 64];
  float4 a0 = make_float4(p0.x + p1.x, p0.y + p1.y, p0.z + p1.z, p0.w + p1.w);
  float4 a1 = make_float4(p2.x + p3.x, p2.y + p3.y, p2.z + p3.z, p2.w + p3.w);
  float s = a0.x*a0.x + a0.y*a0.y + a0.z*a0.z + a0.w*a0.w
          + a1.x*a1.x + a1.y*a1.y + a1.z*a1.z + a1.w*a1.w;
  #pragma unroll
  for (int o = 32; o; o >>= 1) s += __shfl_xor(s, o);
  float sc = rsqrtf(s * (1.0f / DIM) + 1e-6f);
  const bf16* ur = u + (size_t)row * DIM;
  bf16* gr = g + (size_t)row * DIM;
  int c0 = l * 4, c1 = 256 + l * 4;
  gr[c0 + 0] = __float2bfloat16(__bfloat162float(ur[c0 + 0]) * a0.x * sc * w[c0 + 0]);
  gr[c0 + 1] = __float2bfloat16(__bfloat162float(ur[c0 + 1]) * a0.y * sc * w[c0 + 1]);
  gr[c0 + 2] = __float2bfloat16(__bfloat162float(ur[c0 + 2]) * a0.z * sc * w[c0 + 2]);
  gr[c0 + 3] = __float2bfloat16(__bfloat162float(ur[c0 + 3]) * a0.w * sc * w[c0 + 3]);
  gr[c1 + 0] = __float2bfloat16(__bfloat162float(ur[c1 + 0]) * a1.x * sc * w[c1 + 0]);
  gr[c1 + 1] = __float2bfloat16(__bfloat162float(ur[c1 + 1]) * a1.y * sc * w[c1 + 1]);
  gr[c1 + 2] = __float2bfloat16(__bfloat162float(ur[c1 + 2]) * a1.z * sc * w[c1 + 2]);
  gr[c1 + 3] = __float2bfloat16(__bfloat162float(ur[c1 + 3]) * a1.w * sc * w[c1 + 3]);
}

// ---------- out = residual + gated @ wo^T, 128x64 tiles, 256 blocks ----------
__global__ __launch_bounds__(256) void gemm_out_k(const bf16* __restrict__ gated,
                                                  const bf16* __restrict__ wob,
                                                  const float* __restrict__ residual,
                                                  float* __restrict__ out) {
  int bm = blockIdx.x >> 3, bn = blockIdx.x & 7;
  int t = threadIdx.x, w = t >> 6, l = t & 63;
  int ln = l & 15, l4 = (l >> 4) * 4, g8 = (l >> 4) * 8;
  __shared__ __align__(16) short lds[6144];  // A tile [128][32], B tile [64][32]
  f32x4 acc[2][4];
  #pragma unroll
  for (int m = 0; m < 2; ++m)
    #pragma unroll
    for (int n = 0; n < 4; ++n) { f32x4 z = {0.f, 0.f, 0.f, 0.f}; acc[m][n] = z; }

  for (int kt = 0; kt < 16; ++kt) {
    if (kt) __syncthreads();
    #pragma unroll
    for (int i = 0; i < 3; ++i) {
      int s = i * 4 + w;               // 0..11; 0-7 A, 8-11 B
      int col = kt * 32 + (l & 3) * 8;
      const bf16* g;
      if (s < 8) { int row = s * 16 + (l >> 2); g = gated + (size_t)(bm * 128 + row) * DIM + col; }
      else       { int r2 = (s - 8) * 16 + (l >> 2); g = wob + (size_t)(bn * 64 + r2) * DIM + col; }
      gld_lds16(g, lds + s * 512 + l * 8);
    }
    __syncthreads();
    short8 a[2], b[4];
    #pragma unroll
    for (int m = 0; m < 2; ++m)
      a[m] = *(const short8*)(lds + (w * 32 + m * 16 + ln) * 32 + g8);
    #pragma unroll
    for (int n = 0; n < 4; ++n)
      b[n] = *(const short8*)(lds + 4096 + (n * 16 + ln) * 32 + g8);
    #pragma unroll
    for (int m = 0; m < 2; ++m)
      #pragma unroll
      for (int n = 0; n < 4; ++n)
        acc[m][n] = __builtin_amdgcn_mfma_f32_16x16x32_bf16(a[m], b[n], acc[m][n], 0, 0, 0);
  }

  #pragma unroll
  for (int m = 0; m < 2; ++m)
    #pragma unroll
    for (int n = 0; n < 4; ++n)
      #pragma unroll
      for (int j = 0; j < 4; ++j) {
        int rg = bm * 128 + w * 32 + m * 16 + l4 + j;
        int cg = bn * 64 + n * 16 + ln;
        size_t idx = (size_t)rg * DIM + cg;
        out[idx] = acc[m][n][j] + residual[idx];
      }
}

extern "C" void kernel_launch(void* const* d_in, const int* in_sizes, int n_in,
                              void* d_out, int out_size, void* d_ws, size_t ws_size,
                              hipStream_t stream) {
  const float* hidden    = (const float*)d_in[0];
  // d_in[1] = attention_mask (causal tril) — recomputed analytically
  const int*   ts        = (const int*)d_in[2];
  const float* ln_w      = (const float*)d_in[3];
  const float* attn_ln_w = (const float*)d_in[4];
  const float* wq        = (const float*)d_in[5];
  const float* wk        = (const float*)d_in[6];
  const float* wv        = (const float*)d_in[7];
  const float* wu        = (const float*)d_in[8];
  const float* wo        = (const float*)d_in[9];
  const float* ts_w      = (const float*)d_in[10];
  const float* pos_w     = (const float*)d_in[11];

  // OUTPUTS ARE FLOAT32: out [4,1024,512] then attn [4,8,1024,1024]
  float* out  = (float*)d_out;
  float* attn = out + 2097152;

  // workspace (~48 MiB < proven 56 MiB)
  bf16* wb    = (bf16*)d_ws;           // 5 * 512*512
  bf16* hb    = wb + 5 * DIM * DIM;    // [4096,512]
  bf16* q     = hb + 2097152;          // [b,h,l,d]
  bf16* k     = q + 2097152;
  bf16* v     = k + 2097152;           // [b,h,l,d]
  bf16* vT    = v + 2097152;           // [b,h,d,l]
  bf16* u     = vT + 2097152;          // [4096,512]
  bf16* gated = u + 2097152;           // [4096,512]
  float* ao0  = (float*)(gated + 2097152);  // [4096,512] f32
  float* ao1  = ao0 + 2097152;              // [4096,512] f32

  convert_w_k<<<dim3(256, 5), 256, 0, stream>>>(wq, wk, wv, wu, wo, wb);
  rmsnorm_k<<<4096, 64, 0, stream>>>(hidden, ln_w, hb);
  gemm_qkvu_k<<<dim3(128, 4), 256, 0, stream>>>(hb, wb, q, k, v, u);
  transpose_v_k<<<dim3(16, 32), 256, 0, stream>>>(v, vT);
  qk_attn_k<<<dim3(36, 32), 256, 0, stream>>>(q, k, ts, ts_w, pos_w, attn);
  pv_k<<<dim3(8, 32, 2), 256, 0, stream>>>(attn, vT, ao0, ao1);
  gated_k<<<4096, 64, 0, stream>>>(ao0, ao1, u, attn_ln_w, gated);
  gemm_out_k<<<256, 256, 0, stream>>>(gated, wb + 4 * DIM * DIM, hidden, out);
}